// Round 1
// baseline (5267.302 us; speedup 1.0000x reference)
//
#include <hip/hip_runtime.h>
#include <stdint.h>
#include <stddef.h>

typedef _Float16 half_t;
typedef __attribute__((ext_vector_type(8))) _Float16 f16x8;
typedef __attribute__((ext_vector_type(16))) float f32x16;
typedef unsigned long long u64;

#define TSEQ 512
#define NSTAGE 521            // 512 + 3*3 fill (cross-layer lag-3)
#define SLOT 32768            // halfs per h slot (32 b x 1024 h)
#define LSTRIDE ((size_t)513 * SLOT)

__device__ __forceinline__ float sigmoidf_(float x) { return 1.f / (1.f + __expf(-x)); }
__device__ __forceinline__ float tanhf_(float x) { return 1.f - 2.f / (__expf(2.f * x) + 1.f); }

__device__ __forceinline__ void async_copy16(const void* g, void* l) {
    __builtin_amdgcn_global_load_lds((const __attribute__((address_space(1))) void*)g,
                                     (__attribute__((address_space(3))) void*)l, 16, 0, 0);
}

// ---- pack weights into per-CU, per-wave MFMA B-fragment order, f32 -> f16 ----
// linear half idx = wg*131072 + wid*16384 + c*512 + lane*8   (wid = kq*2+nt)
// n' = nt*32+(lane&31): gate g = n'>>4, hcol = n'&15, n_glob = g*1024+cu*16+hcol
// k = kq*512 + c*16 + (lane>>5)*8 + j
// Layer 0 K-map: k<512 -> W0 row k (x); 512<=k<1024 -> zero; k>=1024 -> W0 row k-512 (h).
__global__ void wconv_pack(const float* __restrict__ W0, const float* __restrict__ Wl,
                           half_t* __restrict__ WTp) {
    int idx = blockIdx.x * 256 + threadIdx.x;  // 0 .. 2^22-1
    int lane = idx & 63, c = (idx >> 6) & 31, nt = (idx >> 11) & 1;
    int kq = (idx >> 12) & 3, cu = (idx >> 14) & 63, l = idx >> 20;
    int np = nt * 32 + (lane & 31);
    int n = (np >> 4) * 1024 + cu * 16 + (np & 15);
    int kbase = kq * 512 + c * 16 + (lane >> 5) * 8;
    half_t tmp[8];
#pragma unroll
    for (int j = 0; j < 8; ++j) {
        int k = kbase + j;
        float v;
        if (l == 0) {
            if (k < 512) v = W0[(size_t)k * 4096 + n];
            else if (k < 1024) v = 0.f;
            else v = W0[(size_t)(k - 512) * 4096 + n];
        } else {
            v = Wl[((size_t)(l - 1) * 2048 + k) * 4096 + n];
        }
        tmp[j] = (half_t)v;
    }
    *(int4*)(WTp + (size_t)idx * 8) = *(int4*)tmp;
}

// ---- x f32 [32 b][512 t][512 k] -> xb f16 [t][128 c][32 b][8 j], zeros for c>=64 ----
__global__ void xconv(const float* __restrict__ x, half_t* __restrict__ xb) {
    int idx = blockIdx.x * 256 + threadIdx.x;  // 0 .. 2^21-1
    int b = idx & 31, c = (idx >> 5) & 127, t = idx >> 12;
    half_t tmp[8];
#pragma unroll
    for (int j = 0; j < 8; ++j)
        tmp[j] = (c < 64) ? (half_t)x[((size_t)b * 512 + t) * 512 + c * 8 + j] : (half_t)0.f;
    *(int4*)(xb + (size_t)idx * 8) = *(int4*)tmp;
}

// ---- h0 f32 [l][32 b][1024] -> h_out[l] slot 0 blocked [c][b][j] ----
__global__ void hinit(const float* __restrict__ h0, half_t* __restrict__ hO) {
    int idx = blockIdx.x * 256 + threadIdx.x;  // 0..16383
    int b = idx & 31, c = (idx >> 5) & 127, l = idx >> 12;
    half_t tmp[8];
#pragma unroll
    for (int j = 0; j < 8; ++j) tmp[j] = (half_t)h0[(size_t)l * 32768 + b * 1024 + c * 8 + j];
    *(int4*)(hO + (size_t)l * LSTRIDE + (size_t)(c * 32 + b) * 8) = *(int4*)tmp;
}

__global__ void init_flags(int* f, int n) {
    int i = blockIdx.x * blockDim.x + threadIdx.x;
    if (i < n) f[i] = 0;
}

// ---- persistent pipelined LSTM: 256 WGs (1/CU) x 512 threads (8 waves) ----
// WG wg: layer l = wg>>6, cu = wg&63 owns h-cols [cu*16, cu*16+16) of layer l.
// Wave wid: kq = wid>>1 (K quarter of 512), nt = wid&1 (32-col half of the 64 z-cols).
// SPLIT-LAG schedule: stage s, layer l computes t = s - 3l.
// R9 (this round): latency-bound restructure of the sync path.
//  * flags are DENSE (4B stride): one poll round = 1-2 cache lines, not 64.
//  * B1/B4 removed. Each wave's K-slice depends on exactly 32 producer WGs
//    (kq&1 selects which half), so each wave polls its own 32 flags and runs.
//    LDS hazards (zbuf/hbuf reuse) are covered by B2/B3 (barrier => lgkm flush).
//  * publish + flag post by wave 0 only: 16B/lane hbuf copy (2x u64 agent
//    stores), own s_waitcnt vmcnt(0), lane 0 posts flag. Flag leaves ~0.5us
//    earlier and the other 7 waves never wait on the drain.
//  * asm memory clobber after each poll loop stops the compiler from hoisting
//    the A-fragment loads above the flag check (HW side is ordered by the
//    branch's control dependency on the poll load).
__global__ void __launch_bounds__(512, 2) lstm_pipe(
        const half_t* __restrict__ WTp, const half_t* __restrict__ xb,
        const float* __restrict__ b0, const float* __restrict__ bl,
        const float* __restrict__ c0, half_t* __restrict__ hO,
        int* __restrict__ flags) {
    __shared__ char smem[132096];              // init: 128K weight staging; steady: zbuf+hbuf
    float* zbuf = (float*)smem;                // alias: [col 64][row 128+1 pad] f32 = 33 KB
    half_t* hbuf = (half_t*)(smem + 131072);   // [512] halfs

    const int tid = threadIdx.x;
    const int wg = blockIdx.x;
    const int l = wg >> 6, cu = wg & 63;
    const int lane = tid & 63, wid = tid >> 6;
    const int kq = wid >> 1, nt = wid & 1;
    const bool skipq = (l == 0 && kq == 1);  // zero-padded K region of layer 0

    // ---- stage weights (256 KB/WG) into LDS in two 128 KB halves, then into regs ----
    f16x8 bfr[32];
    {
        const char* wgw = (const char*)(WTp + (size_t)wg * 131072);
#pragma unroll
        for (int it = 0; it < 16; ++it)
            async_copy16(wgw + it * 8192 + tid * 16, smem + it * 8192 + tid * 16);
        __syncthreads();
        if (wid < 4) {
#pragma unroll
            for (int c = 0; c < 32; ++c)
                bfr[c] = *(const f16x8*)(smem + (wid * 32 + c) * 1024 + lane * 16);
        }
        __syncthreads();
#pragma unroll
        for (int it = 0; it < 16; ++it)
            async_copy16(wgw + 131072 + it * 8192 + tid * 16, smem + it * 8192 + tid * 16);
        __syncthreads();
        if (wid >= 4) {
#pragma unroll
            for (int c = 0; c < 32; ++c)
                bfr[c] = *(const f16x8*)(smem + ((wid - 4) * 32 + c) * 1024 + lane * 16);
        }
        __syncthreads();
    }

    // ---- gate-phase mapping ----
    const int b = tid & 31, hc = tid >> 5;  // b in [0,32), hc in [0,16)
    const int colg = cu * 16 + hc;
    const float* bias = (l == 0) ? b0 : (bl + (size_t)(l - 1) * 4096);
    const float bi = bias[colg], bf = bias[1024 + colg];
    const float bg = bias[2048 + colg], bo = bias[3072 + colg];
    float c_reg = c0[(size_t)l * 32768 + b * 1024 + colg];

    half_t* houtl = hO + (size_t)l * LSTRIDE;
    const half_t* hin_base = (l == 0) ? xb : (hO + (size_t)(l - 1) * LSTRIDE);

    // A-frag lane offset within a slot: chunk (kq&1)*64 + 2c + (lane>>5), halfs [b][j]
    const size_t aoff = (size_t)((kq & 1) * 64 + (lane >> 5)) * 256 + (size_t)(lane & 31) * 8;

    // each wave's K-slice covers producer cols [(kq&1)*512, +512) of its source
    // layer => exactly 32 producer WGs.  x-waves (kq<2, l>0) watch layer l-1;
    // h-waves (kq>=2) watch layer l.  (2 lanes share one flag; same line.)
    const int src_layer = (kq < 2) ? (l > 0 ? l - 1 : 0) : l;
    const int* fpoll = flags + src_layer * 64 + (kq & 1) * 32 + (lane & 31);

    for (int s = 0; s < NSTAGE; ++s) {
        const int t = s - 3 * l;
        const bool active = (t >= 0 && t < TSEQ);
        if (active) {
            f32x16 acc;
#pragma unroll
            for (int r = 0; r < 16; ++r) acc[r] = 0.f;
            if (!skipq) {
                const half_t* ap;
                if (kq < 2) {
                    // x-part: lower layer published slot t+1 at its stage s-2;
                    // poll >= s-1 (one stage of margin, normally instant).
                    if (l > 0) {
                        while (__hip_atomic_load(fpoll, __ATOMIC_RELAXED,
                                                 __HIP_MEMORY_SCOPE_AGENT) < s - 1)
                            __builtin_amdgcn_s_sleep(1);
                        ap = hin_base + (size_t)(t + 1) * SLOT + aoff;
                    } else {
                        ap = xb + (size_t)t * SLOT + aoff;
                    }
                } else {
                    // h-part: own layer's slot t published at end of stage s-1.
                    if (t >= 1) {
                        while (__hip_atomic_load(fpoll, __ATOMIC_RELAXED,
                                                 __HIP_MEMORY_SCOPE_AGENT) < s)
                            __builtin_amdgcn_s_sleep(1);
                    }
                    ap = houtl + (size_t)t * SLOT + aoff;
                }
                asm volatile("" ::: "memory");  // keep loads below the poll
                f16x8 ar[32];
#pragma unroll
                for (int p = 0; p < 32; ++p) ar[p] = *(const f16x8*)(ap + (size_t)p * 512);
#pragma unroll
                for (int c = 0; c < 32; ++c)
                    acc = __builtin_amdgcn_mfma_f32_32x32x16_f16(ar[c], bfr[c], acc, 0, 0, 0);
            }
            // ---- zbuf (transposed, stride 129: conflict-free write & read) ----
            {
                int col = nt * 32 + (lane & 31);
                float* zc = zbuf + col * 129 + kq * 32 + 4 * (lane >> 5);
#pragma unroll
                for (int r = 0; r < 16; ++r) zc[(r & 3) + 8 * (r >> 2)] = acc[r];
            }
            __syncthreads();  // B2: partials ready (also fences prior-stage LDS reuse)
            // ---- gates: thread (b, hc) sums 4 K-quarter partials per gate ----
            {
                float zg4[4];
#pragma unroll
                for (int gi = 0; gi < 4; ++gi) {
                    const float* zc = zbuf + (gi * 16 + hc) * 129 + b;
                    zg4[gi] = (zc[0] + zc[32]) + (zc[64] + zc[96]);
                }
                float zi = zg4[0] + bi, zf = zg4[1] + bf;
                float zg = zg4[2] + bg, zo = zg4[3] + bo;
                c_reg = sigmoidf_(zf) * c_reg + sigmoidf_(zi) * tanhf_(zg);
                float h = sigmoidf_(zo) * tanhf_(c_reg);
                hbuf[(hc >> 3) * 256 + b * 8 + (hc & 7)] = (half_t)h;
            }
            __syncthreads();  // B3: hbuf complete
            // ---- publish h slot t+1: wave 0 only, then post flag itself ----
            if (wid == 0) {
                u64 v0 = ((const u64*)hbuf)[2 * lane];
                u64 v1 = ((const u64*)hbuf)[2 * lane + 1];
                u64* dst = (u64*)(houtl + (size_t)(t + 1) * SLOT) + (size_t)cu * 128 + 2 * lane;
                __hip_atomic_store(dst, v0, __ATOMIC_RELAXED, __HIP_MEMORY_SCOPE_AGENT);
                __hip_atomic_store(dst + 1, v1, __ATOMIC_RELAXED, __HIP_MEMORY_SCOPE_AGENT);
                asm volatile("s_waitcnt vmcnt(0)" ::: "memory");  // sc1 stores at coherence pt
                if (lane == 0 && s < NSTAGE - 1)
                    __hip_atomic_store(&flags[wg], s + 1, __ATOMIC_RELAXED,
                                       __HIP_MEMORY_SCOPE_AGENT);
            }
        } else {
            // inactive stage: nothing published, but consumers still count stages
            if (tid == 0 && s < NSTAGE - 1)
                __hip_atomic_store(&flags[wg], s + 1, __ATOMIC_RELAXED,
                                   __HIP_MEMORY_SCOPE_AGENT);
        }
    }
}

// ---- head: out[b][o] = sum_k h_last[b][k] * Wout[k][o] + bout[o] ----
// h_last = hO layer3 slot 512, blocked [k>>3][b][k&7]
__global__ void head_gemm(const half_t* __restrict__ hO, const float* __restrict__ Wout,
                          const float* __restrict__ bout, float* __restrict__ out) {
    int o = blockIdx.x * 32 + (threadIdx.x & 31);
    int b = blockIdx.y * 8 + (threadIdx.x >> 5);
    const half_t* h = hO + (size_t)3 * LSTRIDE + (size_t)512 * SLOT + b * 8;
    float acc = 0.f;
    for (int kb = 0; kb < 128; ++kb) {
        const half_t* hp = h + (size_t)kb * 256;
#pragma unroll
        for (int j = 0; j < 8; ++j)
            acc += (float)hp[j] * Wout[(size_t)(kb * 8 + j) * 1024 + o];
    }
    out[b * 1024 + o] = acc + bout[o];
}

extern "C" void kernel_launch(void* const* d_in, const int* in_sizes, int n_in,
                              void* d_out, int out_size, void* d_ws, size_t ws_size,
                              hipStream_t stream) {
    const float* x    = (const float*)d_in[0];
    const float* h0   = (const float*)d_in[1];
    const float* c0   = (const float*)d_in[2];
    const float* W0   = (const float*)d_in[3];
    const float* b0   = (const float*)d_in[4];
    const float* Wl   = (const float*)d_in[5];
    const float* bl   = (const float*)d_in[6];
    const float* Wout = (const float*)d_in[7];
    const float* bout = (const float*)d_in[8];
    float* out = (float*)d_out;

    char* ws = (char*)d_ws;
    size_t off = 0;
    auto alloc = [&](size_t bytes) {
        size_t r = off;
        off = (off + bytes + 255) & ~(size_t)255;
        return r;
    };
    half_t* WTp = (half_t*)(ws + alloc((size_t)4 * 64 * 131072 * 2));  // 67.1 MB
    half_t* xb  = (half_t*)(ws + alloc((size_t)512 * SLOT * 2));       // 33.6 MB
    half_t* hO  = (half_t*)(ws + alloc((size_t)4 * LSTRIDE * 2));      // 134.5 MB
    int* flags  = (int*)(ws + alloc((size_t)256 * 16 * 4));

    wconv_pack<<<16384, 256, 0, stream>>>(W0, Wl, WTp);
    xconv<<<8192, 256, 0, stream>>>(x, xb);
    hinit<<<64, 256, 0, stream>>>(h0, hO);
    init_flags<<<16, 256, 0, stream>>>(flags, 256 * 16);

    lstm_pipe<<<256, 512, 0, stream>>>(WTp, xb, b0, bl, c0, hO, flags);

    head_gemm<<<dim3(32, 4), 256, 0, stream>>>(hO, Wout, bout, out);
}

// Round 3
// 3855.042 us; speedup vs baseline: 1.3663x; 1.3663x over previous
//
#include <hip/hip_runtime.h>
#include <stdint.h>
#include <stddef.h>

typedef _Float16 half_t;
typedef __attribute__((ext_vector_type(8))) _Float16 f16x8;
typedef __attribute__((ext_vector_type(16))) float f32x16;
typedef unsigned long long u64;

#define TSEQ 512
#define NSTAGE 521            // 512 + 3*3 fill (cross-layer lag-3)
#define SLOT 32768            // halfs per h slot (32 b x 1024 h)
#define LSTRIDE ((size_t)513 * SLOT)

__device__ __forceinline__ float sigmoidf_(float x) { return 1.f / (1.f + __expf(-x)); }
__device__ __forceinline__ float tanhf_(float x) { return 1.f - 2.f / (__expf(2.f * x) + 1.f); }

__device__ __forceinline__ void async_copy16(const void* g, void* l) {
    __builtin_amdgcn_global_load_lds((const __attribute__((address_space(1))) void*)g,
                                     (__attribute__((address_space(3))) void*)l, 16, 0, 0);
}

// ---- pack weights into per-CU, per-wave MFMA B-fragment order, f32 -> f16 ----
// linear half idx = wg*131072 + wid*16384 + c*512 + lane*8   (wid = kq*2+nt)
// n' = nt*32+(lane&31): gate g = n'>>4, hcol = n'&15, n_glob = g*1024+cu*16+hcol
// k = kq*512 + c*16 + (lane>>5)*8 + j
// Layer 0 K-map: k<512 -> W0 row k (x); 512<=k<1024 -> zero; k>=1024 -> W0 row k-512 (h).
__global__ void wconv_pack(const float* __restrict__ W0, const float* __restrict__ Wl,
                           half_t* __restrict__ WTp) {
    int idx = blockIdx.x * 256 + threadIdx.x;  // 0 .. 2^22-1
    int lane = idx & 63, c = (idx >> 6) & 31, nt = (idx >> 11) & 1;
    int kq = (idx >> 12) & 3, cu = (idx >> 14) & 63, l = idx >> 20;
    int np = nt * 32 + (lane & 31);
    int n = (np >> 4) * 1024 + cu * 16 + (np & 15);
    int kbase = kq * 512 + c * 16 + (lane >> 5) * 8;
    half_t tmp[8];
#pragma unroll
    for (int j = 0; j < 8; ++j) {
        int k = kbase + j;
        float v;
        if (l == 0) {
            if (k < 512) v = W0[(size_t)k * 4096 + n];
            else if (k < 1024) v = 0.f;
            else v = W0[(size_t)(k - 512) * 4096 + n];
        } else {
            v = Wl[((size_t)(l - 1) * 2048 + k) * 4096 + n];
        }
        tmp[j] = (half_t)v;
    }
    *(int4*)(WTp + (size_t)idx * 8) = *(int4*)tmp;
}

// ---- x f32 [32 b][512 t][512 k] -> xb f16 [t][128 c][32 b][8 j], zeros for c>=64 ----
__global__ void xconv(const float* __restrict__ x, half_t* __restrict__ xb) {
    int idx = blockIdx.x * 256 + threadIdx.x;  // 0 .. 2^21-1
    int b = idx & 31, c = (idx >> 5) & 127, t = idx >> 12;
    half_t tmp[8];
#pragma unroll
    for (int j = 0; j < 8; ++j)
        tmp[j] = (c < 64) ? (half_t)x[((size_t)b * 512 + t) * 512 + c * 8 + j] : (half_t)0.f;
    *(int4*)(xb + (size_t)idx * 8) = *(int4*)tmp;
}

// ---- h0 f32 [l][32 b][1024] -> h_out[l] slot 0 blocked [c][b][j] ----
__global__ void hinit(const float* __restrict__ h0, half_t* __restrict__ hO) {
    int idx = blockIdx.x * 256 + threadIdx.x;  // 0..16383
    int b = idx & 31, c = (idx >> 5) & 127, l = idx >> 12;
    half_t tmp[8];
#pragma unroll
    for (int j = 0; j < 8; ++j) tmp[j] = (half_t)h0[(size_t)l * 32768 + b * 1024 + c * 8 + j];
    *(int4*)(hO + (size_t)l * LSTRIDE + (size_t)(c * 32 + b) * 8) = *(int4*)tmp;
}

__global__ void init_flags(int* f, int n) {
    int i = blockIdx.x * blockDim.x + threadIdx.x;
    if (i < n) f[i] = 0;
}

// ---- persistent pipelined LSTM: 256 WGs (1/CU) x 512 threads (8 waves) ----
// WG wg: layer l = wg>>6, cu = wg&63 owns h-cols [cu*16, cu*16+16) of layer l.
// Wave wid: kq = wid>>1 (K quarter of 512), nt = wid&1 (32-col half of the 64 z-cols).
// SPLIT-LAG schedule: stage s, layer l computes t = s - 3l.
// R10: per-wave sync restructure, with PADDED flags (R9 post-mortem: dense 4B
// flags serialized 64 writers onto 2 hot lines -> +55%; each writer must own a
// private 64B line; the reader-side 32/64-line gather is ONE parallel load).
//  * B1/B4 removed. Each wave's K-slice depends on exactly 32 producer WGs
//    ((kq&1) selects the half), so each wave polls its own 32 flags.
//    LDS hazards are covered by B2/B3 (barrier implies lgkm flush).
//  * x-waves (kq<2): A-fragment loads issued PRE-poll (R8 induction: this
//    wave's poll at stage s-1 with threshold s-2 proved layer l-1 published
//    slot t+1). The poll (threshold s-1) only seeds the NEXT stage's pre-load,
//    so it runs AFTER the MFMA, off the critical path. To keep the induction
//    seeded across the fill period, x-waves also poll during inactive stages
//    (R8 polled unconditionally for the same reason).
//  * h-waves (kq>=2): poll own-layer half >= s, then load slot t. This is the
//    intra-layer critical path; detect is per-wave (32 producers, not 64+64).
//  * publish + flag post by wave 0 only: 16B/lane hbuf copy (2x u64 agent
//    stores), own s_waitcnt vmcnt(0), lane 0 posts the flag. Flag leaves right
//    after a 1-wave drain instead of after an 8-wave B4 drain.
__global__ void __launch_bounds__(512, 2) lstm_pipe(
        const half_t* __restrict__ WTp, const half_t* __restrict__ xb,
        const float* __restrict__ b0, const float* __restrict__ bl,
        const float* __restrict__ c0, half_t* __restrict__ hO,
        int* __restrict__ flags) {
    __shared__ char smem[132096];              // init: 128K weight staging; steady: zbuf+hbuf
    float* zbuf = (float*)smem;                // alias: [col 64][row 128+1 pad] f32 = 33 KB
    half_t* hbuf = (half_t*)(smem + 131072);   // [512] halfs

    const int tid = threadIdx.x;
    const int wg = blockIdx.x;
    const int l = wg >> 6, cu = wg & 63;
    const int lane = tid & 63, wid = tid >> 6;
    const int kq = wid >> 1, nt = wid & 1;
    const bool skipq = (l == 0 && kq == 1);  // zero-padded K region of layer 0

    // ---- stage weights (256 KB/WG) into LDS in two 128 KB halves, then into regs ----
    f16x8 bfr[32];
    {
        const char* wgw = (const char*)(WTp + (size_t)wg * 131072);
#pragma unroll
        for (int it = 0; it < 16; ++it)
            async_copy16(wgw + it * 8192 + tid * 16, smem + it * 8192 + tid * 16);
        __syncthreads();
        if (wid < 4) {
#pragma unroll
            for (int c = 0; c < 32; ++c)
                bfr[c] = *(const f16x8*)(smem + (wid * 32 + c) * 1024 + lane * 16);
        }
        __syncthreads();
#pragma unroll
        for (int it = 0; it < 16; ++it)
            async_copy16(wgw + 131072 + it * 8192 + tid * 16, smem + it * 8192 + tid * 16);
        __syncthreads();
        if (wid >= 4) {
#pragma unroll
            for (int c = 0; c < 32; ++c)
                bfr[c] = *(const f16x8*)(smem + ((wid - 4) * 32 + c) * 1024 + lane * 16);
        }
        __syncthreads();
    }

    // ---- gate-phase mapping ----
    const int b = tid & 31, hc = tid >> 5;  // b in [0,32), hc in [0,16)
    const int colg = cu * 16 + hc;
    const float* bias = (l == 0) ? b0 : (bl + (size_t)(l - 1) * 4096);
    const float bi = bias[colg], bf = bias[1024 + colg];
    const float bg = bias[2048 + colg], bo = bias[3072 + colg];
    float c_reg = c0[(size_t)l * 32768 + b * 1024 + colg];

    half_t* houtl = hO + (size_t)l * LSTRIDE;
    const half_t* hin_base = (l == 0) ? xb : (hO + (size_t)(l - 1) * LSTRIDE);

    // A-frag lane offset within a slot: chunk (kq&1)*64 + 2c + (lane>>5), halfs [b][j]
    const size_t aoff = (size_t)((kq & 1) * 64 + (lane >> 5)) * 256 + (size_t)(lane & 31) * 8;

    // per-wave poll target: h-waves watch own layer, x-waves (l>0) watch layer
    // l-1; half (kq&1) selects the 32 producer WGs covering this wave's K rows.
    // 2 lanes share each flag; flags padded to 64B (16 ints) = private line.
    const bool is_h = (kq >= 2);
    const int* fpoll = nullptr;
    if (is_h)
        fpoll = flags + (size_t)(l * 64 + (kq & 1) * 32 + (lane & 31)) * 16;
    else if (l > 0)
        fpoll = flags + (size_t)((l - 1) * 64 + (kq & 1) * 32 + (lane & 31)) * 16;

    for (int s = 0; s < NSTAGE; ++s) {
        const int t = s - 3 * l;
        const bool active = (t >= 0 && t < TSEQ);
        if (active) {
            f32x16 acc;
#pragma unroll
            for (int r = 0; r < 16; ++r) acc[r] = 0.f;
            if (!skipq) {
                f16x8 ar[32];
                if (!is_h) {
                    // x-part: pre-load (publish proven by this wave's stage s-1 poll)
                    const half_t* ap = (l == 0) ? (xb + (size_t)t * SLOT + aoff)
                                                : (hin_base + (size_t)(t + 1) * SLOT + aoff);
#pragma unroll
                    for (int p = 0; p < 32; ++p) ar[p] = *(const f16x8*)(ap + (size_t)p * 512);
                } else {
                    // h-part: own layer's slot t published at end of stage s-1
                    if (t >= 1) {
                        while (__hip_atomic_load(fpoll, __ATOMIC_RELAXED,
                                                 __HIP_MEMORY_SCOPE_AGENT) < s)
                            __builtin_amdgcn_s_sleep(1);
                    }
                    asm volatile("" ::: "memory");  // keep loads below the poll
                    const half_t* ap = houtl + (size_t)t * SLOT + aoff;
#pragma unroll
                    for (int p = 0; p < 32; ++p) ar[p] = *(const f16x8*)(ap + (size_t)p * 512);
                }
#pragma unroll
                for (int c = 0; c < 32; ++c)
                    acc = __builtin_amdgcn_mfma_f32_32x32x16_f16(ar[c], bfr[c], acc, 0, 0, 0);
                if (!is_h && l > 0) {
                    // seed stage s+1's pre-load; off the MFMA critical path
                    while (__hip_atomic_load(fpoll, __ATOMIC_RELAXED,
                                             __HIP_MEMORY_SCOPE_AGENT) < s - 1)
                        __builtin_amdgcn_s_sleep(1);
                    asm volatile("" ::: "memory");
                }
            }
            // ---- zbuf (transposed, stride 129: conflict-free write & read) ----
            {
                int col = nt * 32 + (lane & 31);
                float* zc = zbuf + col * 129 + kq * 32 + 4 * (lane >> 5);
#pragma unroll
                for (int r = 0; r < 16; ++r) zc[(r & 3) + 8 * (r >> 2)] = acc[r];
            }
            __syncthreads();  // B2: partials ready (also fences prior-stage LDS reuse)
            // ---- gates: thread (b, hc) sums 4 K-quarter partials per gate ----
            {
                float zg4[4];
#pragma unroll
                for (int gi = 0; gi < 4; ++gi) {
                    const float* zc = zbuf + (gi * 16 + hc) * 129 + b;
                    zg4[gi] = (zc[0] + zc[32]) + (zc[64] + zc[96]);
                }
                float zi = zg4[0] + bi, zf = zg4[1] + bf;
                float zg = zg4[2] + bg, zo = zg4[3] + bo;
                c_reg = sigmoidf_(zf) * c_reg + sigmoidf_(zi) * tanhf_(zg);
                float h = sigmoidf_(zo) * tanhf_(c_reg);
                hbuf[(hc >> 3) * 256 + b * 8 + (hc & 7)] = (half_t)h;
            }
            __syncthreads();  // B3: hbuf complete
            // ---- publish h slot t+1: wave 0 only, then post flag itself ----
            if (wid == 0) {
                u64 v0 = ((const u64*)hbuf)[2 * lane];
                u64 v1 = ((const u64*)hbuf)[2 * lane + 1];
                u64* dst = (u64*)(houtl + (size_t)(t + 1) * SLOT) + (size_t)cu * 128 + 2 * lane;
                __hip_atomic_store(dst, v0, __ATOMIC_RELAXED, __HIP_MEMORY_SCOPE_AGENT);
                __hip_atomic_store(dst + 1, v1, __ATOMIC_RELAXED, __HIP_MEMORY_SCOPE_AGENT);
                asm volatile("s_waitcnt vmcnt(0)" ::: "memory");  // stores at coherence pt
                if (lane == 0 && s < NSTAGE - 1)
                    __hip_atomic_store(&flags[wg * 16], s + 1, __ATOMIC_RELAXED,
                                       __HIP_MEMORY_SCOPE_AGENT);
            }
        } else {
            // inactive fill stage: x-waves keep the pre-load induction seeded
            if (!is_h && l > 0 && t < 0 && s >= 2) {
                while (__hip_atomic_load(fpoll, __ATOMIC_RELAXED,
                                         __HIP_MEMORY_SCOPE_AGENT) < s - 1)
                    __builtin_amdgcn_s_sleep(1);
            }
            // nothing published, but consumers still count stages
            if (tid == 0 && s < NSTAGE - 1)
                __hip_atomic_store(&flags[wg * 16], s + 1, __ATOMIC_RELAXED,
                                   __HIP_MEMORY_SCOPE_AGENT);
        }
    }
}

// ---- head: out[b][o] = sum_k h_last[b][k] * Wout[k][o] + bout[o] ----
// h_last = hO layer3 slot 512, blocked [k>>3][b][k&7]
__global__ void head_gemm(const half_t* __restrict__ hO, const float* __restrict__ Wout,
                          const float* __restrict__ bout, float* __restrict__ out) {
    int o = blockIdx.x * 32 + (threadIdx.x & 31);
    int b = blockIdx.y * 8 + (threadIdx.x >> 5);
    const half_t* h = hO + (size_t)3 * LSTRIDE + (size_t)512 * SLOT + b * 8;
    float acc = 0.f;
    for (int kb = 0; kb < 128; ++kb) {
        const half_t* hp = h + (size_t)kb * 256;
#pragma unroll
        for (int j = 0; j < 8; ++j)
            acc += (float)hp[j] * Wout[(size_t)(kb * 8 + j) * 1024 + o];
    }
    out[b * 1024 + o] = acc + bout[o];
}

extern "C" void kernel_launch(void* const* d_in, const int* in_sizes, int n_in,
                              void* d_out, int out_size, void* d_ws, size_t ws_size,
                              hipStream_t stream) {
    const float* x    = (const float*)d_in[0];
    const float* h0   = (const float*)d_in[1];
    const float* c0   = (const float*)d_in[2];
    const float* W0   = (const float*)d_in[3];
    const float* b0   = (const float*)d_in[4];
    const float* Wl   = (const float*)d_in[5];
    const float* bl   = (const float*)d_in[6];
    const float* Wout = (const float*)d_in[7];
    const float* bout = (const float*)d_in[8];
    float* out = (float*)d_out;

    char* ws = (char*)d_ws;
    size_t off = 0;
    auto alloc = [&](size_t bytes) {
        size_t r = off;
        off = (off + bytes + 255) & ~(size_t)255;
        return r;
    };
    half_t* WTp = (half_t*)(ws + alloc((size_t)4 * 64 * 131072 * 2));  // 67.1 MB
    half_t* xb  = (half_t*)(ws + alloc((size_t)512 * SLOT * 2));       // 33.6 MB
    half_t* hO  = (half_t*)(ws + alloc((size_t)4 * LSTRIDE * 2));      // 134.5 MB
    int* flags  = (int*)(ws + alloc((size_t)256 * 16 * 4));

    wconv_pack<<<16384, 256, 0, stream>>>(W0, Wl, WTp);
    xconv<<<8192, 256, 0, stream>>>(x, xb);
    hinit<<<64, 256, 0, stream>>>(h0, hO);
    init_flags<<<16, 256, 0, stream>>>(flags, 256 * 16);

    lstm_pipe<<<256, 512, 0, stream>>>(WTp, xb, b0, bl, c0, hO, flags);

    head_gemm<<<dim3(32, 4), 256, 0, stream>>>(hO, Wout, bout, out);
}